// Round 13
// baseline (10859.294 us; speedup 1.0000x reference)
//
#include <hip/hip_runtime.h>
#include <hip/hip_fp16.h>

#define BSZ   64
#define ILEN  1024
#define TLEN  1024
#define TTOT  2048
#define IDIM  128
#define HDIM  256
#define GDIM  1024   // 4*HDIM
#define NCLS  128

typedef unsigned int u32;
typedef _Float16 f16x8 __attribute__((ext_vector_type(8)));
typedef float f32x4 __attribute__((ext_vector_type(4)));
typedef _Float16 h2_t __attribute__((ext_vector_type(2)));

union U4H8 { uint4 u; f16x8 h; };

__device__ __forceinline__ float fdot2(u32 a, u32 b, float acc) {
#if __has_builtin(__builtin_amdgcn_fdot2)
    union { u32 u; h2_t h; } ua, ub;
    ua.u = a; ub.u = b;
    return __builtin_amdgcn_fdot2(ua.h, ub.h, acc, false);
#else
    union { u32 u; __half2 h; } ua, ub;
    ua.u = a; ub.u = b;
    return acc + __low2float(ua.h) * __low2float(ub.h)
               + __high2float(ua.h) * __high2float(ub.h);
#endif
}

__device__ __forceinline__ u32 packf2(float x, float y) {
    __half2 h = __floats2half2_rn(x, y);
    union { __half2 h; u32 u; } c; c.h = h;
    return c.u;
}

__device__ __forceinline__ void unpk2(u32 v, float& a, float& b) {
    union { u32 u; __half2 h; } c; c.u = v;
    a = __low2float(c.h); b = __high2float(c.h);
}

__device__ __forceinline__ float sigm(float x) { return 1.f / (1.f + __expf(-x)); }
__device__ __forceinline__ float tanh_fast(float x) { return 1.f - 2.f / (__expf(2.f * x) + 1.f); }

// ---------------------------------------------------------------------------
// Pack weights. Apack/Aipack: MFMA A-frag order (verified R6-R12).
//  Apack  (w_hh): chunk ci = ug5*32 + g*8 + kt, lane l, j holds
//       w_hh[g*256 + ug5*16 + (l&15)][kt*32 + (l>>4)*8 + j]
//  Aipack (w_ih): chunk ci = ug5*16 + g*4 + kt4, same row mapping
//  Wcq (clf): [k4][n] uint4    Wiq (w_ih rows for xproj): [k4][1024 rows]
// ---------------------------------------------------------------------------
__global__ void pack_kernel(const float* __restrict__ w_ih,
                            const float* __restrict__ w_hh,
                            const float* __restrict__ clf_w,
                            uint4* __restrict__ Apack,
                            uint4* __restrict__ Aipack,
                            uint4* __restrict__ Wcq,
                            uint4* __restrict__ Wiq)
{
    int i = blockIdx.x * blockDim.x + threadIdx.x;
    if (i < 32768) {                       // Apack
        int ci = i >> 6, l = i & 63;
        int ug = ci >> 5, g = (ci >> 3) & 3, kt = ci & 7;
        int R  = g * HDIM + ug * 16 + (l & 15);
        int K0 = kt * 32 + (l >> 4) * 8;
        const float* src = w_hh + (size_t)R * HDIM + K0;
        uint4 v;
        v.x = packf2(src[0], src[1]); v.y = packf2(src[2], src[3]);
        v.z = packf2(src[4], src[5]); v.w = packf2(src[6], src[7]);
        Apack[i] = v;
    } else if (i < 49152) {                // Aipack
        int r = i - 32768;
        int ci = r >> 6, l = r & 63;
        int ug = ci >> 4, g = (ci >> 2) & 3, kt4 = ci & 3;
        int R  = g * HDIM + ug * 16 + (l & 15);
        int K0 = kt4 * 32 + (l >> 4) * 8;
        const float* src = w_ih + (size_t)R * IDIM + K0;
        uint4 v;
        v.x = packf2(src[0], src[1]); v.y = packf2(src[2], src[3]);
        v.z = packf2(src[4], src[5]); v.w = packf2(src[6], src[7]);
        Aipack[r] = v;
    } else if (i < 53248) {                // Wcq (clf)
        int r = i - 49152;
        int n = r & (NCLS - 1);
        int k4 = r >> 7;
        const float* src = clf_w + (size_t)n * HDIM + k4 * 8;
        uint4 v;
        v.x = packf2(src[0], src[1]); v.y = packf2(src[2], src[3]);
        v.z = packf2(src[4], src[5]); v.w = packf2(src[6], src[7]);
        Wcq[r] = v;
    } else if (i < 69632) {                // Wiq: [k4 0..15][1024 rows]
        int r = i - 53248;
        int j = r & (GDIM - 1);
        int k4 = r >> 10;
        const float* src = w_ih + (size_t)j * IDIM + k4 * 8;
        uint4 v;
        v.x = packf2(src[0], src[1]); v.y = packf2(src[2], src[3]);
        v.z = packf2(src[4], src[5]); v.w = packf2(src[6], src[7]);
        Wiq[r] = v;
    }
}

// ---------------------------------------------------------------------------
// xproj (zx mode only): zx[t][b][g] = bias[g] + x[b][t]·w_ih[g], f16.
// Block = (b, 8-step t-tile). 17 GFLOP total, trivial for the full chip.
// ---------------------------------------------------------------------------
__global__ __launch_bounds__(256) void xproj_kernel(
    const float* __restrict__ inp,
    const uint4* __restrict__ Wiq,
    const float* __restrict__ bias_g,
    u32* __restrict__ zx)          // [1024 t][64 b][512 u32]
{
    __shared__ alignas(16) uint4 xsh[8][16];   // 8 t x 128 k f16
    const int tid = threadIdx.x;
    const int b   = blockIdx.x >> 7;
    const int t0  = (blockIdx.x & 127) * 8;

    if (tid < 128) {
        int tt = tid >> 4, k4 = tid & 15;
        const float* xr = inp + ((size_t)b * ILEN + t0 + tt) * IDIM + k4 * 8;
        float4 a0 = *(const float4*)xr;
        float4 a1 = *(const float4*)(xr + 4);
        uint4 v;
        v.x = packf2(a0.x, a0.y); v.y = packf2(a0.z, a0.w);
        v.z = packf2(a1.x, a1.y); v.w = packf2(a1.z, a1.w);
        xsh[tt][k4] = v;
    }
    __syncthreads();

    const float b0 = bias_g[2 * tid], b1 = bias_g[2 * tid + 1];
    const float b2 = bias_g[512 + 2 * tid], b3 = bias_g[513 + 2 * tid];
    float acc[8][4];
    #pragma unroll
    for (int tt = 0; tt < 8; ++tt) {
        acc[tt][0] = b0; acc[tt][1] = b1; acc[tt][2] = b2; acc[tt][3] = b3;
    }
    for (int k4 = 0; k4 < 16; ++k4) {
        uint4 w0 = Wiq[k4 * GDIM + 2 * tid];
        uint4 w1 = Wiq[k4 * GDIM + 2 * tid + 1];
        uint4 w2 = Wiq[k4 * GDIM + 512 + 2 * tid];
        uint4 w3 = Wiq[k4 * GDIM + 513 + 2 * tid];
        #pragma unroll
        for (int tt = 0; tt < 8; ++tt) {
            uint4 xv = xsh[tt][k4];
            acc[tt][0] = fdot2(w0.w, xv.w, fdot2(w0.z, xv.z, fdot2(w0.y, xv.y, fdot2(w0.x, xv.x, acc[tt][0]))));
            acc[tt][1] = fdot2(w1.w, xv.w, fdot2(w1.z, xv.z, fdot2(w1.y, xv.y, fdot2(w1.x, xv.x, acc[tt][1]))));
            acc[tt][2] = fdot2(w2.w, xv.w, fdot2(w2.z, xv.z, fdot2(w2.y, xv.y, fdot2(w2.x, xv.x, acc[tt][2]))));
            acc[tt][3] = fdot2(w3.w, xv.w, fdot2(w3.z, xv.z, fdot2(w3.y, xv.y, fdot2(w3.x, xv.x, acc[tt][3]))));
        }
    }
    #pragma unroll
    for (int tt = 0; tt < 8; ++tt) {
        u32* zp = zx + ((size_t)(t0 + tt) * BSZ + b) * 512;
        zp[tid]       = packf2(acc[tt][0], acc[tt][1]);
        zp[tid + 256] = packf2(acc[tt][2], acc[tt][3]);
    }
}

// ---------------------------------------------------------------------------
// Recurrent kernel: 4 PLAIN blocks, 512 threads (8 waves), ZERO inter-block
// communication. Block p owns batches [p*16,+16) and ALL 1024 gates.
// Wave w owns units [w*32,+32) x 4 gates = 8 A-tiles (gg 0..3, ug 0..1).
// W_hh residency: kt0-3 in VGPRs (128/lane), kt6-7 in LDS (128 KB),
// kt4-5 streamed from L2 (L2-resident, 128 KB/step). h: double-buffered
// 16.5 KB LDS + ONE __syncthreads per step. LDS 148.5 KB forces 1 block/CU;
// 8 waves force 2 waves/SIMD; so <=256 VGPR has zero occupancy downside ->
// compiler keeps the hoisted weights (R4's remat trap is structurally gone).
// ZX=true: x-projection preloaded (zx); ZX=false: stream W_ih + pack x.
// ---------------------------------------------------------------------------
template<bool ZX>
__global__ __launch_bounds__(512, 2) void lstm_rec(
    const float* __restrict__ inp,
    const float* __restrict__ bias_g,
    const uint4* __restrict__ Apack,
    const uint4* __restrict__ Aipack,
    const u32* __restrict__ zx,
    __half* __restrict__ Hs)
{
    __shared__ alignas(16) uint4 whL[128 * 64];   // 128 KB: kt 6,7
    __shared__ alignas(16) uint4 hx[2][16 * 33];  // 16.5 KB: h dbuf, padded rows
    __shared__ alignas(16) float bias_sh[1024];   // 4 KB

    const int p   = blockIdx.x;        // batch tile
    const int tid = threadIdx.x;
    const int w   = tid >> 6;          // wave 0..7: units [w*32, +32)
    const int l   = tid & 63;
    const int lq  = l >> 4;
    const int lm  = l & 15;            // batch within tile / B-col

    // ---- stage whL (kt 6,7): chunk = tau*2+k2, tau = w2*8+gg*2+ug
    for (int s = 0; s < 16; ++s) {
        int i = s * 512 + tid;
        int chunk = i >> 6, l2 = i & 63;
        int k2 = chunk & 1, tau = chunk >> 1;
        int w2 = tau >> 3, gg = (tau >> 1) & 3, ug = tau & 1;
        whL[i] = Apack[(((w2 * 2 + ug) * 32) + gg * 8 + 6 + k2) * 64 + l2];
    }
    // ---- zero h buffers
    {
        u32* z = (u32*)hx;
        for (int i = tid; i < 2 * 16 * 33 * 4; i += 512) z[i] = 0u;
    }
    bias_sh[tid] = bias_g[tid];
    bias_sh[tid + 512] = bias_g[tid + 512];

    // ---- hoist W_hh kt0-3 into registers (128 VGPRs), pin vs remat
    uint4 wA[4][2][4];   // [gg][ug][kt]
    #pragma unroll
    for (int gg = 0; gg < 4; ++gg)
        #pragma unroll
        for (int ug = 0; ug < 2; ++ug)
            #pragma unroll
            for (int kt = 0; kt < 4; ++kt)
                wA[gg][ug][kt] = Apack[(((w * 2 + ug) * 32) + gg * 8 + kt) * 64 + l];
    #pragma unroll
    for (int gg = 0; gg < 4; ++gg)
        #pragma unroll
        for (int ug = 0; ug < 2; ++ug)
            #pragma unroll
            for (int kt = 0; kt < 4; ++kt)
                asm volatile("" : "+v"(wA[gg][ug][kt].x), "+v"(wA[gg][ug][kt].y),
                                  "+v"(wA[gg][ug][kt].z), "+v"(wA[gg][ug][kt].w));

    float cS[2][4] = {{0.f, 0.f, 0.f, 0.f}, {0.f, 0.f, 0.f, 0.f}};

    __syncthreads();   // staging done

    for (int t = 0; t < TTOT; ++t) {
        const int par = t & 1;

        // ---- early issues (before the barrier/compute; latency hides)
        uint2 zxv[4][2];
        uint4 bx4[4];
        if (ZX) {
            if (t < ILEN) {
                const u32* zb = zx + ((size_t)t * BSZ + p * 16 + lm) * 512
                              + w * 16 + lq * 2;
                #pragma unroll
                for (int gg = 0; gg < 4; ++gg)
                    #pragma unroll
                    for (int ug = 0; ug < 2; ++ug)
                        zxv[gg][ug] = *(const uint2*)(zb + gg * 128 + ug * 8);
            }
        } else {
            if (t < ILEN) {
                const float* xr = inp + ((size_t)(p * 16 + lm) * ILEN + t) * IDIM + lq * 8;
                #pragma unroll
                for (int k4 = 0; k4 < 4; ++k4) {
                    float4 a0 = *(const float4*)(xr + k4 * 32);
                    float4 a1 = *(const float4*)(xr + k4 * 32 + 4);
                    bx4[k4].x = packf2(a0.x, a0.y); bx4[k4].y = packf2(a0.z, a0.w);
                    bx4[k4].z = packf2(a1.x, a1.y); bx4[k4].w = packf2(a1.z, a1.w);
                }
            }
        }

        __syncthreads();   // hx[par] (written at end of t-1) visible

        f32x4 acc[4][2];
        #pragma unroll
        for (int gg = 0; gg < 4; ++gg)
            #pragma unroll
            for (int ug = 0; ug < 2; ++ug)
                acc[gg][ug] = (f32x4){0.f, 0.f, 0.f, 0.f};

        // ---- h-MFMAs: kt0-3 A from VGPR
        #pragma unroll
        for (int kt = 0; kt < 4; ++kt) {
            U4H8 b; b.u = hx[par][lm * 33 + kt * 4 + lq];
            #pragma unroll
            for (int gg = 0; gg < 4; ++gg)
                #pragma unroll
                for (int ug = 0; ug < 2; ++ug) {
                    U4H8 a; a.u = wA[gg][ug][kt];
                    acc[gg][ug] = __builtin_amdgcn_mfma_f32_16x16x32_f16(a.h, b.h, acc[gg][ug], 0, 0, 0);
                }
        }
        // ---- kt4-5: A streamed from L2 (Apack resident in L2)
        #pragma unroll
        for (int kt = 4; kt < 6; ++kt) {
            U4H8 b; b.u = hx[par][lm * 33 + kt * 4 + lq];
            #pragma unroll
            for (int gg = 0; gg < 4; ++gg)
                #pragma unroll
                for (int ug = 0; ug < 2; ++ug) {
                    U4H8 a; a.u = Apack[(((w * 2 + ug) * 32) + gg * 8 + kt) * 64 + l];
                    acc[gg][ug] = __builtin_amdgcn_mfma_f32_16x16x32_f16(a.h, b.h, acc[gg][ug], 0, 0, 0);
                }
        }
        // ---- kt6-7: A from LDS
        #pragma unroll
        for (int kt = 6; kt < 8; ++kt) {
            U4H8 b; b.u = hx[par][lm * 33 + kt * 4 + lq];
            #pragma unroll
            for (int gg = 0; gg < 4; ++gg)
                #pragma unroll
                for (int ug = 0; ug < 2; ++ug) {
                    U4H8 a; a.u = whL[(((w * 8 + gg * 2 + ug) * 2) + kt - 6) * 64 + l];
                    acc[gg][ug] = __builtin_amdgcn_mfma_f32_16x16x32_f16(a.h, b.h, acc[gg][ug], 0, 0, 0);
                }
        }
        // ---- x-part (fallback only): A = Aipack streamed
        if (!ZX && t < ILEN) {
            #pragma unroll
            for (int k4 = 0; k4 < 4; ++k4) {
                U4H8 b; b.u = bx4[k4];
                #pragma unroll
                for (int gg = 0; gg < 4; ++gg)
                    #pragma unroll
                    for (int ug = 0; ug < 2; ++ug) {
                        U4H8 a; a.u = Aipack[(((w * 2 + ug) * 16) + gg * 4 + k4) * 64 + l];
                        acc[gg][ug] = __builtin_amdgcn_mfma_f32_16x16x32_f16(a.h, b.h, acc[gg][ug], 0, 0, 0);
                    }
            }
        }

        // ---- epilogue: add zx/bias, gates, c/h update, write h to LDS
        #pragma unroll
        for (int ug = 0; ug < 2; ++ug) {
            float ez[4][4];   // [gg][r]
            if (ZX && t < ILEN) {
                #pragma unroll
                for (int gg = 0; gg < 4; ++gg) {
                    unpk2(zxv[gg][ug].x, ez[gg][0], ez[gg][1]);
                    unpk2(zxv[gg][ug].y, ez[gg][2], ez[gg][3]);
                }
            } else {
                #pragma unroll
                for (int gg = 0; gg < 4; ++gg) {
                    f32x4 bv = *(const f32x4*)&bias_sh[gg * 256 + w * 32 + ug * 16 + lq * 4];
                    ez[gg][0] = bv[0]; ez[gg][1] = bv[1]; ez[gg][2] = bv[2]; ez[gg][3] = bv[3];
                }
            }
            float hv[4];
            #pragma unroll
            for (int r = 0; r < 4; ++r) {
                float zi = acc[0][ug][r] + ez[0][r];
                float zf = acc[1][ug][r] + ez[1][r];
                float zg = acc[2][ug][r] + ez[2][r];
                float zo = acc[3][ug][r] + ez[3][r];
                float ig = sigm(zi);
                float fg = sigm(zf);
                float gv = tanh_fast(zg);
                float og = sigm(zo);
                cS[ug][r] = fg * cS[ug][r] + ig * gv;
                hv[r] = og * tanh_fast(cS[ug][r]);
            }
            uint2 pv;
            pv.x = packf2(hv[0], hv[1]);
            pv.y = packf2(hv[2], hv[3]);
            ((uint2*)&hx[par ^ 1][0])[lm * 66 + w * 8 + ug * 4 + lq] = pv;
            if (t >= ILEN) {
                u32* hs = (u32*)(Hs + ((size_t)(p * 16 + lm) * TLEN + (t - ILEN)) * HDIM
                                 + w * 32 + ug * 16 + lq * 4);
                *(uint2*)hs = pv;
            }
        }
        // single barrier per step lives at the top of the next iteration
    }
}

// ---------------------------------------------------------------------------
// Classifier: out[b][t][n] = clf_b[n] + clf_w[n]·h[b][t]. (unchanged)
// ---------------------------------------------------------------------------
#define CTT 16
__global__ __launch_bounds__(256) void clf_kernel(
    const uint4* __restrict__ Wcq,
    const __half* __restrict__ Hs,
    const float* __restrict__ clf_b,
    float* __restrict__ out)
{
    __shared__ alignas(16) u32 h_sh[CTT * (HDIM / 2)];   // 8 KB
    const int tid = threadIdx.x;
    const int b  = blockIdx.x >> 6;
    const int t0 = (blockIdx.x & 63) * CTT;

    const uint4* hsrc = (const uint4*)(Hs + ((size_t)b * TLEN + t0) * HDIM);
    uint4* hdst = (uint4*)h_sh;
    hdst[tid]       = hsrc[tid];
    hdst[tid + 256] = hsrc[tid + 256];
    __syncthreads();

    const int n  = tid & (NCLS - 1);
    const int tl = tid >> 7;
    const float bias = clf_b[n];
    float acc[8];
    #pragma unroll
    for (int q = 0; q < 8; ++q) acc[q] = bias;

    #pragma unroll 4
    for (int k4 = 0; k4 < HDIM / 8; ++k4) {
        uint4 w = Wcq[k4 * NCLS + n];
        #pragma unroll
        for (int q = 0; q < 8; ++q) {
            const uint4* hp = (const uint4*)(h_sh + (tl + 2 * q) * (HDIM / 2));
            uint4 h = hp[k4];
            acc[q] = fdot2(w.x, h.x, acc[q]);
            acc[q] = fdot2(w.y, h.y, acc[q]);
            acc[q] = fdot2(w.z, h.z, acc[q]);
            acc[q] = fdot2(w.w, h.w, acc[q]);
        }
    }
    #pragma unroll
    for (int q = 0; q < 8; ++q) {
        out[((size_t)b * TLEN + t0 + tl + 2 * q) * NCLS + n] = acc[q];
    }
}

// ---------------------------------------------------------------------------
extern "C" void kernel_launch(void* const* d_in, const int* in_sizes, int n_in,
                              void* d_out, int out_size, void* d_ws, size_t ws_size,
                              hipStream_t stream)
{
    const float* inp   = (const float*)d_in[0];
    // d_in[1] = tlen (1024, hardcoded)
    const float* w_ih  = (const float*)d_in[2];
    const float* w_hh  = (const float*)d_in[3];
    const float* bias  = (const float*)d_in[4];
    const float* clf_w = (const float*)d_in[5];
    const float* clf_b = (const float*)d_in[6];
    float* out = (float*)d_out;

    char* ws = (char*)d_ws;
    uint4*  Apack  = (uint4*)(ws);                    // 512 KB
    uint4*  Aipack = (uint4*)(ws + 524288);           // 256 KB
    uint4*  Wcq    = (uint4*)(ws + 786432);           // 64 KB
    uint4*  Wiq    = (uint4*)(ws + 851968);           // 256 KB
    __half* Hs     = (__half*)(ws + 1114112);         // 33.55 MB
    u32*    zx     = (u32*)(ws + 34668544);           // 128 MB (zx mode only)
    const size_t need_zx = 34668544ULL + 134217728ULL;

    pack_kernel<<<272, 256, 0, stream>>>(w_ih, w_hh, clf_w, Apack, Aipack, Wcq, Wiq);

    if (ws_size >= need_zx) {
        xproj_kernel<<<BSZ * 128, 256, 0, stream>>>(inp, Wiq, bias, zx);
        lstm_rec<true><<<4, 512, 0, stream>>>(inp, bias, Apack, Aipack, zx, Hs);
    } else {
        lstm_rec<false><<<4, 512, 0, stream>>>(inp, bias, Apack, Aipack, nullptr, Hs);
    }

    clf_kernel<<<BSZ * (TLEN / CTT), 256, 0, stream>>>(Wcq, Hs, clf_b, out);
}